// Round 6
// baseline (491.428 us; speedup 1.0000x reference)
//
#include <hip/hip_runtime.h>
#include <hip/hip_bf16.h>

#define D 1024
#define H 16
#define KN 32768
#define EPS 1e-5f
#define NB 256          // blocks
#define RPB 128         // neighbor rows per block

// ws float offsets
#define O_Q     0
#define O_QK    1024
#define O_SB    17408
#define O_LH    17424
#define O_CTX   17440
#define O_XB    18464
#define O_XLN   19488
#define O_H1    20512
#define O_Y     24608
#define O_NBUF  25632
#define O_LPART 42016
#define O_BAR   46112   // 64 ints
#define O_PART  46176   // 16-byte aligned (46176*4 % 16 == 0)

__device__ __forceinline__ float wave_sum(float v){
  #pragma unroll
  for (int off = 32; off; off >>= 1) v += __shfl_xor(v, off, 64);
  return v;
}

#define GLL(gp, lp) __builtin_amdgcn_global_load_lds((const __attribute__((address_space(1))) void*)(gp), (__attribute__((address_space(3))) void*)(lp), 16, 0, 0)

__device__ __forceinline__ void gbar(int* bar, int idx){
  __syncthreads();                       // drains vmcnt/lgkmcnt for all block stores
  if (threadIdx.x == 0){
    int* cnt = bar + idx*2;
    int* gen = bar + idx*2 + 1;
    __threadfence();                     // release our stores device-wide
    int g = atomicAdd(gen, 0);
    if (atomicAdd(cnt, 1) == (int)gridDim.x - 1){
      atomicExch(cnt, 0);
      atomicAdd(gen, 1);
    } else {
      while (atomicAdd(gen, 0) == g){ __builtin_amdgcn_s_sleep(2); }
    }
    __threadfence();                     // acquire: invalidate stale lines
  }
  __syncthreads();
}

__global__ void g_init(int* bar){
  if (threadIdx.x < 64) bar[threadIdx.x] = 0;
}

__global__ __launch_bounds__(1024) void g_fused(
    const float* __restrict__ query, const float* __restrict__ nbr,
    const float* __restrict__ ipw,   const float* __restrict__ ipb,
    const float* __restrict__ opw,   const float* __restrict__ opb,
    const float* __restrict__ w1,    const float* __restrict__ b1,
    const float* __restrict__ w2,    const float* __restrict__ b2v,
    const float* __restrict__ g1,    const float* __restrict__ be1,
    const float* __restrict__ g2,    const float* __restrict__ be2,
    float* __restrict__ ws, float* __restrict__ out){

  float* q     = ws + O_Q;
  float* qk    = ws + O_QK;
  float* sb    = ws + O_SB;
  float* lh    = ws + O_LH;
  float* ctx   = ws + O_CTX;
  float* xb    = ws + O_XB;
  float* xln   = ws + O_XLN;
  float* h1    = ws + O_H1;
  float* y     = ws + O_Y;
  float* nbuf  = ws + O_NBUF;
  float* lpart = ws + O_LPART;
  int*   bar   = (int*)(ws + O_BAR);
  float* part  = ws + O_PART;

  __shared__ __align__(16) float tile[2][8*D];   // 64 KiB
  __shared__ float smem[1056];                   // xs[1024] | red[16] | bc[2]
  float* xs  = smem;
  float* red = smem + 1024;
  float* bcs = smem + 1040;

  const int b = blockIdx.x, t = threadIdx.x;
  const int w = t >> 6, l = t & 63;

  // ---------- A1: q[j] = query . wq_row(j) + bq[j]  (waves 0..3, j = 4b+w)
  if (w < 4){
    int j = b*4 + w;
    const float4* qv = (const float4*)(query + l*16);
    const float4* wv = (const float4*)(ipw + (size_t)j*D + l*16);
    float a = 0.f;
    #pragma unroll
    for (int c = 0; c < 4; c++){
      float4 aa = qv[c], bb = wv[c];
      a += aa.x*bb.x + aa.y*bb.y + aa.z*bb.z + aa.w*bb.w;
    }
    a = wave_sum(a);
    if (l == 0) q[j] = a + ipb[j];
  }
  gbar(bar, 0);

  // ---------- A2: qk[h][col], sb[h].  h = b>>4, col slice = (b&15)*64
  {
    int h = b >> 4, sl = b & 15;
    int col = sl*64 + l;
    float par = 0.f;
    #pragma unroll
    for (int i = 0; i < 4; i++){
      int j = w*4 + i;
      par += q[h*64 + j] * ipw[(size_t)(D + h*64 + j)*D + col];
    }
    smem[w*64 + l] = par;
    __syncthreads();
    if (t < 64){
      float s = 0.f;
      #pragma unroll
      for (int jj = 0; jj < 16; jj++) s += smem[jj*64 + t];
      qk[h*D + sl*64 + t] = s;
    }
    if (sl == 0 && w == 1){
      float p = q[h*64 + l] * ipb[D + h*64 + l];
      p = wave_sum(p);
      if (l == 0) sb[h] = p;
    }
    __syncthreads();
  }
  gbar(bar, 1);

  // ---------- B: fused scoreless attention (wave = head, lane owns 16 cols)
  {
    int h = w, ci = l;
    int wb2 = t & ~63;
    float sbh = sb[h];
    float qkv[16];
    {
      const float4* qp = (const float4*)(qk + h*D);
      #pragma unroll
      for (int c = 0; c < 4; c++){
        float4 f = qp[c*64 + ci];
        qkv[4*c]=f.x; qkv[4*c+1]=f.y; qkv[4*c+2]=f.z; qkv[4*c+3]=f.w;
      }
    }
    float acc[16];
    #pragma unroll
    for (int i = 0; i < 16; i++) acc[i] = 0.f;
    float lsum = 0.f;

    const int k0 = b * RPB;
    const uint4* gb2 = (const uint4*)nbr;
    {
      const uint4* g = gb2 + (size_t)k0*256;
      #pragma unroll
      for (int i = 0; i < 2; i++) GLL(g + i*1024 + t, &tile[0][(i*1024 + wb2)*4]);
    }
    __syncthreads();

    #pragma unroll 1
    for (int tl = 0; tl < RPB/8; tl++){
      int cur = tl & 1;
      if (tl + 1 < RPB/8){
        const uint4* g = gb2 + (size_t)(k0 + (tl+1)*8)*256;
        #pragma unroll
        for (int i = 0; i < 2; i++) GLL(g + i*1024 + t, &tile[cur^1][(i*1024 + wb2)*4]);
      }
      #pragma unroll 1
      for (int r = 0; r < 8; r += 2){
        const float4* rowA = (const float4*)(tile[cur]) + r*256;
        const float4* rowB = rowA + 256;
        float xfA[16], xfB[16], pa[4], pb[4];
        #pragma unroll
        for (int c = 0; c < 4; c++){
          float4 a = rowA[c*64 + ci];
          float4 bb = rowB[c*64 + ci];
          xfA[4*c]=a.x; xfA[4*c+1]=a.y; xfA[4*c+2]=a.z; xfA[4*c+3]=a.w;
          xfB[4*c]=bb.x; xfB[4*c+1]=bb.y; xfB[4*c+2]=bb.z; xfB[4*c+3]=bb.w;
          pa[c] = a.x*qkv[4*c] + a.y*qkv[4*c+1] + a.z*qkv[4*c+2] + a.w*qkv[4*c+3];
          pb[c] = bb.x*qkv[4*c] + bb.y*qkv[4*c+1] + bb.z*qkv[4*c+2] + bb.w*qkv[4*c+3];
        }
        float sA = (pa[0]+pa[1]) + (pa[2]+pa[3]);
        float sB = (pb[0]+pb[1]) + (pb[2]+pb[3]);
        #pragma unroll
        for (int off = 32; off; off >>= 1){
          sA += __shfl_xor(sA, off, 64);
          sB += __shfl_xor(sB, off, 64);
        }
        float pA = __expf((sA + sbh)*0.125f);
        float pB = __expf((sB + sbh)*0.125f);
        lsum += pA + pB;
        #pragma unroll
        for (int i = 0; i < 16; i++) acc[i] += pA*xfA[i];
        #pragma unroll
        for (int i = 0; i < 16; i++) acc[i] += pB*xfB[i];
      }
      __syncthreads();
    }

    if (ci == 0) lpart[b*H + h] = lsum;
    float4* o = (float4*)(part + (size_t)b*(H*D) + h*D);
    #pragma unroll
    for (int c = 0; c < 4; c++)
      o[c*64 + ci] = make_float4(acc[4*c], acc[4*c+1], acc[4*c+2], acc[4*c+3]);
  }
  gbar(bar, 2);

  // ---------- C: nbuf[o] = sum_blocks part ; lh[h] = sum lpart
  {
    int o = b*64 + l;
    float s = 0.f;
    #pragma unroll
    for (int c = 0; c < 16; c++) s += part[(size_t)(w*16 + c)*(H*D) + o];
    smem[w*64 + l] = s;
    __syncthreads();
    if (t < 64){
      float s2 = 0.f;
      #pragma unroll
      for (int j = 0; j < 16; j++) s2 += smem[j*64 + t];
      nbuf[b*64 + t] = s2;
    }
    if (b == 0 && w == 15 && l < 16){
      float s3 = 0.f;
      #pragma unroll 8
      for (int c = 0; c < NB; c++) s3 += lpart[c*H + l];
      lh[l] = s3;
    }
    __syncthreads();
  }
  gbar(bar, 3);

  // ---------- D: ctx[j] = wv_row(j).(nbuf_h/lh_h) + bv[j]
  if (w < 4){
    int j = b*4 + w, h2 = j >> 6;
    const float4* wv = (const float4*)(ipw + (size_t)(2*D + j)*D + l*16);
    const float4* nv = (const float4*)(nbuf + h2*D + l*16);
    float a = 0.f;
    #pragma unroll
    for (int c = 0; c < 4; c++){
      float4 bb = wv[c], nn = nv[c];
      a += bb.x*nn.x + bb.y*nn.y + bb.z*nn.z + bb.w*nn.w;
    }
    a = wave_sum(a);
    if (l == 0) ctx[j] = a/lh[h2] + ipb[2*D + j];
  }
  gbar(bar, 4);

  // ---------- E: xb[j] = query[j] + opw_row(j).ctx + opb[j]
  if (w < 4){
    int j = b*4 + w;
    const float4* wv = (const float4*)(opw + (size_t)j*D + l*16);
    const float4* cv = (const float4*)(ctx + l*16);
    float a = 0.f;
    #pragma unroll
    for (int c = 0; c < 4; c++){
      float4 bb = wv[c], cc = cv[c];
      a += bb.x*cc.x + bb.y*cc.y + bb.z*cc.z + bb.w*cc.w;
    }
    a = wave_sum(a);
    if (l == 0) xb[j] = query[j] + a + opb[j];
  }
  gbar(bar, 5);

  // ---------- F: LN1 (per-block) + FFN1 (wave w -> row b*16+w)
  {
    float v = xb[t];
    float s = wave_sum(v);
    if (l == 0) red[w] = s;
    __syncthreads();
    if (t == 0){ float a=0.f; for (int i=0;i<16;i++) a += red[i]; bcs[0] = a*(1.0f/D); }
    __syncthreads();
    float m = bcs[0];
    float dd = v - m;
    float s2 = wave_sum(dd*dd);
    if (l == 0) red[w] = s2;
    __syncthreads();
    if (t == 0){ float a=0.f; for (int i=0;i<16;i++) a += red[i]; bcs[1] = a*(1.0f/D); }
    __syncthreads();
    float rs = rsqrtf(bcs[1] + EPS);
    float r = dd*rs*g1[t] + be1[t];
    xs[t] = r;
    if (b == 0) xln[t] = r;
    __syncthreads();

    int j = b*16 + w;
    const float4* wr = (const float4*)(w1 + (size_t)j*D);
    const float4* xs4 = (const float4*)xs;
    float a = 0.f;
    #pragma unroll
    for (int c = 0; c < 4; c++){
      float4 ww = wr[c*64 + l], xx = xs4[c*64 + l];
      a += ww.x*xx.x + ww.y*xx.y + ww.z*xx.z + ww.w*xx.w;
    }
    a = wave_sum(a);
    if (l == 0){
      float z = a + b1[j];
      h1[j] = 0.5f*z*(1.0f + erff(z*0.70710678118654752f));
    }
  }
  gbar(bar, 6);

  // ---------- G: FFN2 (waves 0..3 -> row 4b+w, row length 4096)
  if (w < 4){
    int j = b*4 + w;
    const float4* wv = (const float4*)(w2 + (size_t)j*4096 + l*64);
    const float4* hv = (const float4*)(h1 + l*64);
    float a = 0.f;
    #pragma unroll
    for (int c = 0; c < 16; c++){
      float4 bb = wv[c], hh = hv[c];
      a += bb.x*hh.x + bb.y*hh.y + bb.z*hh.z + bb.w*hh.w;
    }
    a = wave_sum(a);
    if (l == 0) y[j] = a + b2v[j];
  }
  gbar(bar, 7);

  // ---------- H: LN2 -> out (block 0 only)
  if (b == 0){
    float v = xln[t] + y[t];
    float s = wave_sum(v);
    if (l == 0) red[w] = s;
    __syncthreads();
    if (t == 0){ float a=0.f; for (int i=0;i<16;i++) a += red[i]; bcs[0] = a*(1.0f/D); }
    __syncthreads();
    float m = bcs[0];
    float dd = v - m;
    float s2 = wave_sum(dd*dd);
    if (l == 0) red[w] = s2;
    __syncthreads();
    if (t == 0){ float a=0.f; for (int i=0;i<16;i++) a += red[i]; bcs[1] = a*(1.0f/D); }
    __syncthreads();
    float rs = rsqrtf(bcs[1] + EPS);
    out[t] = dd*rs*g2[t] + be2[t];
  }
}

extern "C" void kernel_launch(void* const* d_in, const int* in_sizes, int n_in,
                              void* d_out, int out_size, void* d_ws, size_t ws_size,
                              hipStream_t stream) {
  const float* query = (const float*)d_in[0];
  const float* nbr   = (const float*)d_in[1];
  const float* ipw   = (const float*)d_in[2];
  const float* ipb   = (const float*)d_in[3];
  const float* opw   = (const float*)d_in[4];
  const float* opb   = (const float*)d_in[5];
  const float* w1    = (const float*)d_in[6];
  const float* b1    = (const float*)d_in[7];
  const float* w2    = (const float*)d_in[8];
  const float* b2v   = (const float*)d_in[9];
  const float* g1    = (const float*)d_in[10];
  const float* be1   = (const float*)d_in[11];
  const float* g2    = (const float*)d_in[12];
  const float* be2   = (const float*)d_in[13];

  float* ws = (float*)d_ws;
  g_init <<<1, 64, 0, stream>>>((int*)(ws + O_BAR));
  g_fused<<<NB, 1024, 0, stream>>>(query, nbr, ipw, ipb, opw, opb,
                                   w1, b1, w2, b2v, g1, be1, g2, be2,
                                   ws, (float*)d_out);
}